// Round 1
// 205.987 us; speedup vs baseline: 1.0884x; 1.0884x over previous
//
#include <hip/hip_runtime.h>
#include <hip/hip_bf16.h>

typedef unsigned short u16;
typedef unsigned int u32;
typedef __attribute__((ext_vector_type(4))) float f32x4;
typedef __attribute__((ext_vector_type(4))) u16 u16x4;
typedef __attribute__((ext_vector_type(8))) u16 u16x8;
typedef __attribute__((ext_vector_type(8))) short s16x8;

__device__ __forceinline__ u16 f2bf(float f) {
    union { float f; u32 u; } v; v.f = f;
    u32 r = v.u + 0x7FFFu + ((v.u >> 16) & 1u);
    return (u16)(r >> 16);
}

__device__ __forceinline__ void gl_lds16(const u16* g, u16* l) {
    __builtin_amdgcn_global_load_lds(
        (const __attribute__((address_space(1))) unsigned int*)(const void*)g,
        (__attribute__((address_space(3))) unsigned int*)(void*)l, 16, 0, 0);
}

// ---------------- weight transpose + bf16 convert: Wt[j][c] = W[c][j] ----------------
__global__ __launch_bounds__(256) void wtrans_kernel(
    const float* __restrict__ w0, const float* __restrict__ w1,
    const float* __restrict__ w2, const float* __restrict__ w3,
    u16* __restrict__ dst) {
    __shared__ float t[64][65];
    int wsel = blockIdx.x >> 6;
    int tile = blockIdx.x & 63;
    int j0 = (tile >> 3) * 64, c0 = (tile & 7) * 64;
    const float* src = wsel == 0 ? w0 : wsel == 1 ? w1 : wsel == 2 ? w2 : w3;
    u16* out = dst + (long)wsel * 512 * 512;
    int tj = threadIdx.x & 63;
    int ti = threadIdx.x >> 6;
#pragma unroll
    for (int p = 0; p < 16; ++p) {
        int row = p * 4 + ti;
        t[row][tj] = src[(long)(c0 + row) * 512 + j0 + tj];
    }
    __syncthreads();
#pragma unroll
    for (int p = 0; p < 16; ++p) {
        int jl = p * 4 + ti;
        out[(long)(j0 + jl) * 512 + c0 + tj] = f2bf(t[tj][jl]);
    }
}

// ---------------- permute x -> Aq (16384 x 512 bf16), tiled transpose ----------------
__global__ __launch_bounds__(256) void permx_kernel(const float* __restrict__ x, u16* __restrict__ Aq) {
    __shared__ u16 t[64][36];
    int bid = blockIdx.x;
    int cb = bid & 7; bid >>= 3;
    int y  = bid & 31; bid >>= 5;
    int tt = bid & 3; bid >>= 2;
    int b  = bid;
    int tid = threadIdx.x;
    long ibase = ((long)(b * 512 + cb * 64) * 4 + tt) * 1024 + y * 32;
#pragma unroll
    for (int p = 0; p < 2; ++p) {
        int task = p * 256 + tid;
        int cc = task >> 3, xl = (task & 7) * 4;
        float4 v = *(const float4*)&x[ibase + (long)cc * 4096 + xl];
        u16x4 o = {f2bf(v.x), f2bf(v.y), f2bf(v.z), f2bf(v.w)};
        *(u16x4*)&t[cc][xl] = o;
    }
    __syncthreads();
    {
        int xx = tid >> 3, j = tid & 7;
        u16x8 o;
#pragma unroll
        for (int i = 0; i < 8; ++i) o[i] = t[j * 8 + i][xx];
        int row = b * 4096 + (y >> 1) * 256 + (xx >> 1) * 16 + tt * 4 + (y & 1) * 2 + (xx & 1);
        *(u16x8*)&Aq[(long)row * 512 + cb * 64 + j * 8] = o;
    }
}

// ---------------- permute context -> Actx (65536 x 512 bf16), tiled transpose ----------------
__global__ __launch_bounds__(256) void permc_kernel(const float* __restrict__ ctx, u16* __restrict__ Actx) {
    __shared__ u16 t[64][68];
    int bid = blockIdx.x;
    int cb = bid & 7; bid >>= 3;
    int xb = bid & 1; bid >>= 1;
    int y  = bid & 127; bid >>= 7;
    int b  = bid;
    int tid = threadIdx.x;
    long ibase = ((long)(b * 512 + cb * 64) * 128 + y) * 128 + xb * 64;
#pragma unroll
    for (int p = 0; p < 4; ++p) {
        int task = p * 256 + tid;
        int cc = task >> 4, xl = (task & 15) * 4;
        float4 v = *(const float4*)&ctx[ibase + (long)cc * 16384 + xl];
        u16x4 o = {f2bf(v.x), f2bf(v.y), f2bf(v.z), f2bf(v.w)};
        *(u16x4*)&t[cc][xl] = o;
    }
    __syncthreads();
#pragma unroll
    for (int p = 0; p < 2; ++p) {
        int task = p * 256 + tid;
        int xx = task >> 3, j = task & 7;
        u16x8 o;
#pragma unroll
        for (int i = 0; i < 8; ++i) o[i] = t[j * 8 + i][xx];
        int xg = xb * 64 + xx;
        int row = b * 16384 + (y >> 3) * 1024 + (xg >> 3) * 64 + (y & 7) * 8 + (xg & 7);
        *(u16x8*)&Actx[(long)row * 512 + cb * 64 + j * 8] = o;
    }
}

// ---------------- 128x128-tile bf16 GEMM (Q & final proj), m97 structure ----------------
template <int FINAL>
__global__ __launch_bounds__(256, 4) void gemm128_kernel(
    const u16* __restrict__ A, const u16* __restrict__ Bt,
    u16* __restrict__ Cb, float* __restrict__ Cf, const float* __restrict__ bias) {
    __shared__ u16 As[1024 * 8];
    __shared__ u16 Bs[1024 * 8];
    int tid = threadIdx.x;
    int lane = tid & 63;
    int w = tid >> 6;
    int wm = w >> 1, wn = w & 1;
    int bid = blockIdx.x;
    int wg = (bid & 7) * 64 + (bid >> 3);   // grid 512, XCD chunk swizzle
    int m0 = (wg >> 2) * 128;
    int n0 = (wg & 3) * 128;

    const f32x4 z = {0.f, 0.f, 0.f, 0.f};
    f32x4 acc[4][4];
#pragma unroll
    for (int i = 0; i < 4; ++i)
#pragma unroll
        for (int j = 0; j < 4; ++j) acc[i][j] = z;

    int aoff[4], boff[4], lb[4];
#pragma unroll
    for (int i = 0; i < 4; ++i) {
        int s = i * 256 + tid;
        int row = s >> 3;
        int cb = (s & 7) ^ (row & 7);
        aoff[i] = (m0 + row) * 512 + cb * 8;
        boff[i] = (n0 + row) * 512 + cb * 8;
        lb[i] = (i * 256 + w * 64) * 8;
    }
    int la = lane & 15, lg = lane >> 4;
    for (int ks = 0; ks < 8; ++ks) {
        int ko = ks * 64;
#pragma unroll
        for (int i = 0; i < 4; ++i) {
            gl_lds16(&A[aoff[i] + ko], &As[lb[i]]);
            gl_lds16(&Bt[boff[i] + ko], &Bs[lb[i]]);
        }
        __syncthreads();
#pragma unroll
        for (int kk = 0; kk < 2; ++kk) {
            int cb = kk * 4 + lg;
            s16x8 af[4], bfr[4];
#pragma unroll
            for (int mt = 0; mt < 4; ++mt) {
                int r = wm * 64 + mt * 16 + la;
                af[mt] = *(const s16x8*)&As[r * 64 + ((cb ^ (r & 7)) * 8)];
            }
#pragma unroll
            for (int nt = 0; nt < 4; ++nt) {
                int c = wn * 64 + nt * 16 + la;
                bfr[nt] = *(const s16x8*)&Bs[c * 64 + ((cb ^ (c & 7)) * 8)];
            }
#pragma unroll
            for (int mt = 0; mt < 4; ++mt)
#pragma unroll
                for (int nt = 0; nt < 4; ++nt)
                    acc[mt][nt] = __builtin_amdgcn_mfma_f32_16x16x32_bf16(af[mt], bfr[nt], acc[mt][nt], 0, 0, 0);
        }
        __syncthreads();
    }
#pragma unroll
    for (int mt = 0; mt < 4; ++mt) {
#pragma unroll
        for (int nt = 0; nt < 4; ++nt) {
            int col = n0 + wn * 64 + nt * 16 + la;
#pragma unroll
            for (int rr = 0; rr < 4; ++rr) {
                int r = m0 + wm * 64 + mt * 16 + lg * 4 + rr;
                float v = acc[mt][nt][rr];
                if (FINAL) {
                    int bb = r >> 12, hg = (r >> 8) & 15, wgx = (r >> 4) & 15;
                    int tt = (r >> 2) & 3, rr0 = (r >> 1) & 1, cc0 = r & 1;
                    int tok = bb * 4096 + tt * 1024 + (hg * 2 + rr0) * 32 + wgx * 2 + cc0;
                    Cf[(long)tok * 512 + col] = v + bias[col];
                } else {
                    Cb[(long)r * 512 + col] = f2bf(v);
                }
            }
        }
    }
}

// ---------------- combined K+V GEMM: M=65536 x N=1024 x K=512, 256x256 tile ----------------
// 8 waves (2M x 4N), BK=64, 2 LDS buffers (128 KiB), stage-ahead-2 with COUNTED vmcnt(8):
// per tile t: [compute buf t&1] bar [stage t+2 -> buf t&1] vmcnt(8) bar.  Global loads for
// tile t+2 stay in flight across tile t+1's whole compute phase (never drained to 0 in the
// main loop -> no barrier drain stall).  LDS slot s: row=s>>3, cb=(s&7)^(row&7) via
// pre-swizzled global source, linear gl_lds dest (measured 0 bank conflicts).
// Output KV-interleaved [65536][1024]: cols 0..511 = K, 512..1023 = V.
__global__ __launch_bounds__(512, 2) void gemmkv256_kernel(
    const u16* __restrict__ A, const u16* __restrict__ B, u16* __restrict__ C) {
    __shared__ u16 lds[2][2][16384];   // [buf][A/B][256 rows x 64]
    int tid = threadIdx.x;
    int lane = tid & 63;
    int w = tid >> 6;                  // 0..7
    int wm = w >> 2, wn = w & 3;
    int la = lane & 15, lg = lane >> 4;
    int bid = blockIdx.x;
    int wg = (bid & 7) * 128 + (bid >> 3);   // grid 1024, XCD chunk swizzle (1024%8==0)
    int m0 = (wg >> 2) * 256;
    int n0 = (wg & 3) * 256;

    const f32x4 z = {0.f, 0.f, 0.f, 0.f};
    f32x4 acc[8][4];
#pragma unroll
    for (int i = 0; i < 8; ++i)
#pragma unroll
        for (int j = 0; j < 4; ++j) acc[i][j] = z;

    int aoff[4], boff[4], lsl[4];
#pragma unroll
    for (int i = 0; i < 4; ++i) {
        int s = i * 512 + tid;
        int row = s >> 3;
        int cb = (s & 7) ^ (row & 7);
        aoff[i] = (m0 + row) * 512 + cb * 8;
        boff[i] = (n0 + row) * 512 + cb * 8;
        lsl[i] = (i * 512 + w * 64) * 8;   // wave-uniform LDS base, lane-linear 16B
    }

    auto STAGE = [&](int t, int buf) {
#pragma unroll
        for (int i = 0; i < 4; ++i) {
            gl_lds16(&A[aoff[i] + t * 64], &lds[buf][0][lsl[i]]);
            gl_lds16(&B[boff[i] + t * 64], &lds[buf][1][lsl[i]]);
        }
    };
    auto COMPUTE = [&](int buf) {
        const u16* Ab = lds[buf][0];
        const u16* Bb = lds[buf][1];
#pragma unroll
        for (int kk = 0; kk < 2; ++kk) {
            int cb = kk * 4 + lg;
            s16x8 af[8], bfr[4];
#pragma unroll
            for (int mt = 0; mt < 8; ++mt) {
                int r = wm * 128 + mt * 16 + la;
                af[mt] = *(const s16x8*)&Ab[r * 64 + ((cb ^ (r & 7)) * 8)];
            }
#pragma unroll
            for (int nt = 0; nt < 4; ++nt) {
                int c = wn * 64 + nt * 16 + la;
                bfr[nt] = *(const s16x8*)&Bb[c * 64 + ((cb ^ (c & 7)) * 8)];
            }
            __builtin_amdgcn_s_setprio(1);
#pragma unroll
            for (int mt = 0; mt < 8; ++mt)
#pragma unroll
                for (int nt = 0; nt < 4; ++nt)
                    acc[mt][nt] = __builtin_amdgcn_mfma_f32_16x16x32_bf16(af[mt], bfr[nt], acc[mt][nt], 0, 0, 0);
            __builtin_amdgcn_s_setprio(0);
        }
    };

    STAGE(0, 0);
    STAGE(1, 1);
    asm volatile("s_waitcnt vmcnt(8)" ::: "memory");   // tile0 landed; tile1 in flight
    __builtin_amdgcn_s_barrier();
    asm volatile("" ::: "memory");

#pragma unroll
    for (int t = 0; t < 8; ++t) {
        COMPUTE(t & 1);
        if (t < 6) {
            asm volatile("" ::: "memory");
            __builtin_amdgcn_s_barrier();              // all waves done reading buf t&1
            STAGE(t + 2, t & 1);
            asm volatile("s_waitcnt vmcnt(8)" ::: "memory");  // tile t+1 landed; t+2 in flight
            __builtin_amdgcn_s_barrier();              // publish tile t+1
            asm volatile("" ::: "memory");
        } else if (t == 6) {
            asm volatile("s_waitcnt vmcnt(0)" ::: "memory");  // drain: tile7 landed
            __builtin_amdgcn_s_barrier();
            asm volatile("" ::: "memory");
        }
    }

#pragma unroll
    for (int mt = 0; mt < 8; ++mt) {
#pragma unroll
        for (int nt = 0; nt < 4; ++nt) {
            int col = n0 + wn * 64 + nt * 16 + la;
#pragma unroll
            for (int rr = 0; rr < 4; ++rr) {
                int r = m0 + wm * 128 + mt * 16 + lg * 4 + rr;
                C[(long)r * 1024 + col] = f2bf(acc[mt][nt][rr]);
            }
        }
    }
}

// ---------------- windowed attention: 1 wave per (window, head), KV interleaved ----------------
__global__ __launch_bounds__(64) void attn_kernel(
    const u16* __restrict__ Q, const u16* __restrict__ KV, u16* __restrict__ O) {
    __shared__ u16 P[16 * 104];
    int bid = blockIdx.x;
    int wg = (bid & 7) * 1024 + (bid >> 3);  // same-window heads colocate on an XCD
    int win = wg >> 3;
    int h = wg & 7;
    int lane = threadIdx.x;
    int la = lane & 15, lg = lane >> 4;
    const u16* Qb = Q + (long)win * 16 * 512 + h * 64;
    const u16* Kb = KV + (long)win * 64 * 1024 + h * 64;
    const u16* Vb = KV + (long)win * 64 * 1024 + 512 + h * 64;

    s16x8 qf[2];
#pragma unroll
    for (int kk = 0; kk < 2; ++kk)
        qf[kk] = *(const s16x8*)&Qb[la * 512 + kk * 32 + lg * 8];

    const f32x4 z = {0.f, 0.f, 0.f, 0.f};
    f32x4 st[4];
#pragma unroll
    for (int rt = 0; rt < 4; ++rt) st[rt] = z;
#pragma unroll
    for (int rt = 0; rt < 4; ++rt)
#pragma unroll
        for (int kk = 0; kk < 2; ++kk) {
            s16x8 kf = *(const s16x8*)&Kb[(rt * 16 + la) * 1024 + kk * 32 + lg * 8];
            st[rt] = __builtin_amdgcn_mfma_f32_16x16x32_bf16(kf, qf[kk], st[rt], 0, 0, 0);
        }
    float mloc = -1e30f;
#pragma unroll
    for (int rt = 0; rt < 4; ++rt)
#pragma unroll
        for (int rr = 0; rr < 4; ++rr) {
            st[rt][rr] *= 0.125f;
            mloc = fmaxf(mloc, st[rt][rr]);
        }
    mloc = fmaxf(mloc, __shfl_xor(mloc, 16));
    mloc = fmaxf(mloc, __shfl_xor(mloc, 32));
    float p[4][4];
    float sloc = 0.f;
#pragma unroll
    for (int rt = 0; rt < 4; ++rt)
#pragma unroll
        for (int rr = 0; rr < 4; ++rr) {
            p[rt][rr] = __expf(st[rt][rr] - mloc);
            sloc += p[rt][rr];
        }
    sloc += __shfl_xor(sloc, 16);
    sloc += __shfl_xor(sloc, 32);
    float inv = 1.0f / sloc;
#pragma unroll
    for (int rt = 0; rt < 4; ++rt)
#pragma unroll
        for (int rr = 0; rr < 4; ++rr)
            P[la * 104 + rt * 16 + lg * 4 + rr] = f2bf(p[rt][rr] * inv);
    __syncthreads();

    f32x4 od[4];
#pragma unroll
    for (int dt = 0; dt < 4; ++dt) od[dt] = z;
#pragma unroll
    for (int kk2 = 0; kk2 < 2; ++kk2) {
        s16x8 pa = *(const s16x8*)&P[la * 104 + kk2 * 32 + lg * 8];
#pragma unroll
        for (int dt = 0; dt < 4; ++dt) {
            s16x8 vb;
#pragma unroll
            for (int j = 0; j < 8; ++j)
                vb[j] = (short)Vb[(long)(kk2 * 32 + lg * 8 + j) * 1024 + dt * 16 + la];
            od[dt] = __builtin_amdgcn_mfma_f32_16x16x32_bf16(pa, vb, od[dt], 0, 0, 0);
        }
    }
    u16* Ob = O + (long)win * 16 * 512 + h * 64;
#pragma unroll
    for (int dt = 0; dt < 4; ++dt)
#pragma unroll
        for (int rr = 0; rr < 4; ++rr)
            Ob[(long)(lg * 4 + rr) * 512 + dt * 16 + la] = f2bf(od[dt][rr]);
}

__global__ void sentinel_kernel(float* out) {
    if (threadIdx.x == 0 && blockIdx.x == 0) out[0] = -12345.0f;
}

extern "C" void kernel_launch(void* const* d_in, const int* in_sizes, int n_in,
                              void* d_out, int out_size, void* d_ws, size_t ws_size,
                              hipStream_t stream) {
    const float* x   = (const float*)d_in[0];
    const float* ctx = (const float*)d_in[1];
    const float* Wq  = (const float*)d_in[2];
    const float* Wk  = (const float*)d_in[3];
    const float* Wv  = (const float*)d_in[4];
    const float* Wo  = (const float*)d_in[5];
    const float* bo  = (const float*)d_in[6];
    float* out = (float*)d_out;

    u16* wsb  = (u16*)d_ws;
    u16* WT   = wsb;                    // 4 * 512*512
    u16* Aq   = WT + 4l * 262144;       // 16384*512
    u16* Actx = Aq + 8388608l;          // 65536*512
    u16* Qb   = Actx + 33554432l;       // 16384*512
    u16* KVb  = Qb + 8388608l;          // 65536*1024 (K cols 0..511, V cols 512..1023)
    u16* Ob   = KVb + 67108864l;        // 16384*512
    size_t need = (size_t)(126877696l) * 2;
    if (ws_size < need) {
        sentinel_kernel<<<1, 64, 0, stream>>>(out);
        return;
    }

    wtrans_kernel<<<256, 256, 0, stream>>>(Wq, Wk, Wv, Wo, WT);
    permx_kernel<<<4096, 256, 0, stream>>>(x, Aq);
    permc_kernel<<<8192, 256, 0, stream>>>(ctx, Actx);
    gemm128_kernel<0><<<512, 256, 0, stream>>>(Aq, WT, Qb, nullptr, nullptr);
    gemmkv256_kernel<<<1024, 512, 0, stream>>>(Actx, WT + 262144l, KVb);
    attn_kernel<<<8192, 64, 0, stream>>>(Qb, KVb, Ob);
    gemm128_kernel<1><<<512, 256, 0, stream>>>(Ob, WT + 3l * 262144, nullptr, out, bo);
}

// Round 2
// 203.082 us; speedup vs baseline: 1.1039x; 1.0143x over previous
//
#include <hip/hip_runtime.h>
#include <hip/hip_bf16.h>

typedef unsigned short u16;
typedef unsigned int u32;
typedef __attribute__((ext_vector_type(4))) float f32x4;
typedef __attribute__((ext_vector_type(4))) u16 u16x4;
typedef __attribute__((ext_vector_type(8))) u16 u16x8;
typedef __attribute__((ext_vector_type(8))) short s16x8;

__device__ __forceinline__ u16 f2bf(float f) {
    union { float f; u32 u; } v; v.f = f;
    u32 r = v.u + 0x7FFFu + ((v.u >> 16) & 1u);
    return (u16)(r >> 16);
}

__device__ __forceinline__ void gl_lds16(const u16* g, u16* l) {
    __builtin_amdgcn_global_load_lds(
        (const __attribute__((address_space(1))) unsigned int*)(const void*)g,
        (__attribute__((address_space(3))) unsigned int*)(void*)l, 16, 0, 0);
}

// ---------------- weight transpose + bf16 convert: Wt[j][c] = W[c][j] ----------------
__global__ __launch_bounds__(256) void wtrans_kernel(
    const float* __restrict__ w0, const float* __restrict__ w1,
    const float* __restrict__ w2, const float* __restrict__ w3,
    u16* __restrict__ dst) {
    __shared__ float t[64][65];
    int wsel = blockIdx.x >> 6;
    int tile = blockIdx.x & 63;
    int j0 = (tile >> 3) * 64, c0 = (tile & 7) * 64;
    const float* src = wsel == 0 ? w0 : wsel == 1 ? w1 : wsel == 2 ? w2 : w3;
    u16* out = dst + (long)wsel * 512 * 512;
    int tj = threadIdx.x & 63;
    int ti = threadIdx.x >> 6;
#pragma unroll
    for (int p = 0; p < 16; ++p) {
        int row = p * 4 + ti;
        t[row][tj] = src[(long)(c0 + row) * 512 + j0 + tj];
    }
    __syncthreads();
#pragma unroll
    for (int p = 0; p < 16; ++p) {
        int jl = p * 4 + ti;
        out[(long)(j0 + jl) * 512 + c0 + tj] = f2bf(t[tj][jl]);
    }
}

// ---------------- permute x -> Aq (16384 x 512 bf16), tiled transpose ----------------
__global__ __launch_bounds__(256) void permx_kernel(const float* __restrict__ x, u16* __restrict__ Aq) {
    __shared__ u16 t[64][36];
    int bid = blockIdx.x;
    int cb = bid & 7; bid >>= 3;
    int y  = bid & 31; bid >>= 5;
    int tt = bid & 3; bid >>= 2;
    int b  = bid;
    int tid = threadIdx.x;
    long ibase = ((long)(b * 512 + cb * 64) * 4 + tt) * 1024 + y * 32;
#pragma unroll
    for (int p = 0; p < 2; ++p) {
        int task = p * 256 + tid;
        int cc = task >> 3, xl = (task & 7) * 4;
        float4 v = *(const float4*)&x[ibase + (long)cc * 4096 + xl];
        u16x4 o = {f2bf(v.x), f2bf(v.y), f2bf(v.z), f2bf(v.w)};
        *(u16x4*)&t[cc][xl] = o;
    }
    __syncthreads();
    {
        int xx = tid >> 3, j = tid & 7;
        u16x8 o;
#pragma unroll
        for (int i = 0; i < 8; ++i) o[i] = t[j * 8 + i][xx];
        int row = b * 4096 + (y >> 1) * 256 + (xx >> 1) * 16 + tt * 4 + (y & 1) * 2 + (xx & 1);
        *(u16x8*)&Aq[(long)row * 512 + cb * 64 + j * 8] = o;
    }
}

// ---------------- permute context -> Actx (65536 x 512 bf16), tiled transpose ----------------
__global__ __launch_bounds__(256) void permc_kernel(const float* __restrict__ ctx, u16* __restrict__ Actx) {
    __shared__ u16 t[64][68];
    int bid = blockIdx.x;
    int cb = bid & 7; bid >>= 3;
    int xb = bid & 1; bid >>= 1;
    int y  = bid & 127; bid >>= 7;
    int b  = bid;
    int tid = threadIdx.x;
    long ibase = ((long)(b * 512 + cb * 64) * 128 + y) * 128 + xb * 64;
#pragma unroll
    for (int p = 0; p < 4; ++p) {
        int task = p * 256 + tid;
        int cc = task >> 4, xl = (task & 15) * 4;
        float4 v = *(const float4*)&ctx[ibase + (long)cc * 16384 + xl];
        u16x4 o = {f2bf(v.x), f2bf(v.y), f2bf(v.z), f2bf(v.w)};
        *(u16x4*)&t[cc][xl] = o;
    }
    __syncthreads();
#pragma unroll
    for (int p = 0; p < 2; ++p) {
        int task = p * 256 + tid;
        int xx = task >> 3, j = task & 7;
        u16x8 o;
#pragma unroll
        for (int i = 0; i < 8; ++i) o[i] = t[j * 8 + i][xx];
        int xg = xb * 64 + xx;
        int row = b * 16384 + (y >> 3) * 1024 + (xg >> 3) * 64 + (y & 7) * 8 + (xg & 7);
        *(u16x8*)&Actx[(long)row * 512 + cb * 64 + j * 8] = o;
    }
}

// ---------------- 128x128-tile bf16 GEMM (Q & final proj), m97 structure ----------------
template <int FINAL>
__global__ __launch_bounds__(256, 4) void gemm128_kernel(
    const u16* __restrict__ A, const u16* __restrict__ Bt,
    u16* __restrict__ Cb, float* __restrict__ Cf, const float* __restrict__ bias) {
    __shared__ u16 As[1024 * 8];
    __shared__ u16 Bs[1024 * 8];
    int tid = threadIdx.x;
    int lane = tid & 63;
    int w = tid >> 6;
    int wm = w >> 1, wn = w & 1;
    int bid = blockIdx.x;
    int wg = (bid & 7) * 64 + (bid >> 3);   // grid 512, XCD chunk swizzle
    int m0 = (wg >> 2) * 128;
    int n0 = (wg & 3) * 128;

    const f32x4 z = {0.f, 0.f, 0.f, 0.f};
    f32x4 acc[4][4];
#pragma unroll
    for (int i = 0; i < 4; ++i)
#pragma unroll
        for (int j = 0; j < 4; ++j) acc[i][j] = z;

    int aoff[4], boff[4], lb[4];
#pragma unroll
    for (int i = 0; i < 4; ++i) {
        int s = i * 256 + tid;
        int row = s >> 3;
        int cb = (s & 7) ^ (row & 7);
        aoff[i] = (m0 + row) * 512 + cb * 8;
        boff[i] = (n0 + row) * 512 + cb * 8;
        lb[i] = (i * 256 + w * 64) * 8;
    }
    int la = lane & 15, lg = lane >> 4;
    for (int ks = 0; ks < 8; ++ks) {
        int ko = ks * 64;
#pragma unroll
        for (int i = 0; i < 4; ++i) {
            gl_lds16(&A[aoff[i] + ko], &As[lb[i]]);
            gl_lds16(&Bt[boff[i] + ko], &Bs[lb[i]]);
        }
        __syncthreads();
#pragma unroll
        for (int kk = 0; kk < 2; ++kk) {
            int cb = kk * 4 + lg;
            s16x8 af[4], bfr[4];
#pragma unroll
            for (int mt = 0; mt < 4; ++mt) {
                int r = wm * 64 + mt * 16 + la;
                af[mt] = *(const s16x8*)&As[r * 64 + ((cb ^ (r & 7)) * 8)];
            }
#pragma unroll
            for (int nt = 0; nt < 4; ++nt) {
                int c = wn * 64 + nt * 16 + la;
                bfr[nt] = *(const s16x8*)&Bs[c * 64 + ((cb ^ (c & 7)) * 8)];
            }
#pragma unroll
            for (int mt = 0; mt < 4; ++mt)
#pragma unroll
                for (int nt = 0; nt < 4; ++nt)
                    acc[mt][nt] = __builtin_amdgcn_mfma_f32_16x16x32_bf16(af[mt], bfr[nt], acc[mt][nt], 0, 0, 0);
        }
        __syncthreads();
    }
#pragma unroll
    for (int mt = 0; mt < 4; ++mt) {
#pragma unroll
        for (int nt = 0; nt < 4; ++nt) {
            int col = n0 + wn * 64 + nt * 16 + la;
#pragma unroll
            for (int rr = 0; rr < 4; ++rr) {
                int r = m0 + wm * 64 + mt * 16 + lg * 4 + rr;
                float v = acc[mt][nt][rr];
                if (FINAL) {
                    int bb = r >> 12, hg = (r >> 8) & 15, wgx = (r >> 4) & 15;
                    int tt = (r >> 2) & 3, rr0 = (r >> 1) & 1, cc0 = r & 1;
                    int tok = bb * 4096 + tt * 1024 + (hg * 2 + rr0) * 32 + wgx * 2 + cc0;
                    Cf[(long)tok * 512 + col] = v + bias[col];
                } else {
                    Cb[(long)r * 512 + col] = f2bf(v);
                }
            }
        }
    }
}

// ---------------- combined K+V GEMM: M=65536 x N=1024 x K=512, 256x256 tile ----------------
// 4-phase-per-K-tile schedule (m201-style): phases (mh,kk) in serpentine order
// (0,k0)->(0,k1)->(1,k1)->(1,k0); B fragments register-cached across the tile (read in
// P1/P2, reused in P3/P4).  Each phase: [ds_read subtile; stage; s_barrier; setprio(1);
// 16 MFMA; setprio(0); s_barrier].  Consumption-driven early staging of tile t+2 into
// buf t&1: after P2's post-MFMA barrier the B tile + A row-slots 0,2 are consumed ->
// stage 6/8 gl_lds inside P3/P4, last 2 (A slots 1,3, read through P4) after P4's barrier.
// Counted vmcnt(8) + publish barrier once per tile (loads never drained in main loop).
// Output KV-interleaved [65536][1024]: cols 0..511 = K, 512..1023 = V.
__global__ __launch_bounds__(512, 2) void gemmkv256_kernel(
    const u16* __restrict__ A, const u16* __restrict__ B, u16* __restrict__ C) {
    __shared__ u16 lds[2][2][16384];   // [buf][A/B][256 rows x 64]
    int tid = threadIdx.x;
    int lane = tid & 63;
    int w = tid >> 6;                  // 0..7
    int wm = w >> 2, wn = w & 3;
    int la = lane & 15, lg = lane >> 4;
    int bid = blockIdx.x;
    int wg = (bid & 7) * 128 + (bid >> 3);   // grid 1024, XCD chunk swizzle
    int m0 = (wg >> 2) * 256;
    int n0 = (wg & 3) * 256;

    const f32x4 z = {0.f, 0.f, 0.f, 0.f};
    f32x4 acc[8][4];
#pragma unroll
    for (int i = 0; i < 8; ++i)
#pragma unroll
        for (int j = 0; j < 4; ++j) acc[i][j] = z;

    int aoff[4], boff[4], lsl[4];
#pragma unroll
    for (int i = 0; i < 4; ++i) {
        int s = i * 512 + tid;
        int row = s >> 3;              // slot i covers rows [64i, 64i+64)
        int cb = (s & 7) ^ (row & 7);
        aoff[i] = (m0 + row) * 512 + cb * 8;
        boff[i] = (n0 + row) * 512 + cb * 8;
        lsl[i] = (i * 512 + w * 64) * 8;
    }

    s16x8 bfr[4][2];                   // B fragments, cached across the whole K-tile

    // prologue: stage tiles 0 (buf0) and 1 (buf1)
#pragma unroll
    for (int i = 0; i < 4; ++i) {
        gl_lds16(&A[aoff[i]], &lds[0][0][lsl[i]]);
        gl_lds16(&B[boff[i]], &lds[0][1][lsl[i]]);
    }
#pragma unroll
    for (int i = 0; i < 4; ++i) {
        gl_lds16(&A[aoff[i] + 64], &lds[1][0][lsl[i]]);
        gl_lds16(&B[boff[i] + 64], &lds[1][1][lsl[i]]);
    }
    asm volatile("s_waitcnt vmcnt(8)" ::: "memory");   // tile0 landed; tile1 in flight
    __builtin_amdgcn_s_barrier();
    asm volatile("" ::: "memory");

#pragma unroll
    for (int t = 0; t < 8; ++t) {
        int buf = t & 1;
        const u16* Ab = lds[buf][0];
        const u16* Bb = lds[buf][1];
        int ko2 = (t + 2) * 64;

        // ---- P1: (mh=0, kk=0), load B frags kk=0 ----
        {
            int cb = lg;
            s16x8 af[4];
#pragma unroll
            for (int mt = 0; mt < 4; ++mt) {
                int r = wm * 128 + mt * 16 + la;
                af[mt] = *(const s16x8*)&Ab[r * 64 + ((cb ^ (r & 7)) * 8)];
            }
#pragma unroll
            for (int nt = 0; nt < 4; ++nt) {
                int c = wn * 64 + nt * 16 + la;
                bfr[nt][0] = *(const s16x8*)&Bb[c * 64 + ((cb ^ (c & 7)) * 8)];
            }
            __builtin_amdgcn_s_barrier();
            __builtin_amdgcn_s_setprio(1);
#pragma unroll
            for (int mt = 0; mt < 4; ++mt)
#pragma unroll
                for (int nt = 0; nt < 4; ++nt)
                    acc[mt][nt] = __builtin_amdgcn_mfma_f32_16x16x32_bf16(af[mt], bfr[nt][0], acc[mt][nt], 0, 0, 0);
            __builtin_amdgcn_s_setprio(0);
            __builtin_amdgcn_sched_barrier(0);
            __builtin_amdgcn_s_barrier();
        }
        // ---- P2: (mh=0, kk=1), load B frags kk=1 ----
        {
            int cb = 4 + lg;
            s16x8 af[4];
#pragma unroll
            for (int mt = 0; mt < 4; ++mt) {
                int r = wm * 128 + mt * 16 + la;
                af[mt] = *(const s16x8*)&Ab[r * 64 + ((cb ^ (r & 7)) * 8)];
            }
#pragma unroll
            for (int nt = 0; nt < 4; ++nt) {
                int c = wn * 64 + nt * 16 + la;
                bfr[nt][1] = *(const s16x8*)&Bb[c * 64 + ((cb ^ (c & 7)) * 8)];
            }
            __builtin_amdgcn_s_barrier();
            __builtin_amdgcn_s_setprio(1);
#pragma unroll
            for (int mt = 0; mt < 4; ++mt)
#pragma unroll
                for (int nt = 0; nt < 4; ++nt)
                    acc[mt][nt] = __builtin_amdgcn_mfma_f32_16x16x32_bf16(af[mt], bfr[nt][1], acc[mt][nt], 0, 0, 0);
            __builtin_amdgcn_s_setprio(0);
            __builtin_amdgcn_sched_barrier(0);
            __builtin_amdgcn_s_barrier();
            // B tile + A slots 0,2 now fully consumed by all waves
        }
        // ---- P3: (mh=1, kk=1), B frags reused; stage B slots 0,1 + A slot 0 of t+2 ----
        {
            int cb = 4 + lg;
            s16x8 af[4];
#pragma unroll
            for (int mt = 0; mt < 4; ++mt) {
                int r = wm * 128 + 64 + mt * 16 + la;
                af[mt] = *(const s16x8*)&Ab[r * 64 + ((cb ^ (r & 7)) * 8)];
            }
            if (t < 6) {
                gl_lds16(&B[boff[0] + ko2], &lds[buf][1][lsl[0]]);
                gl_lds16(&B[boff[1] + ko2], &lds[buf][1][lsl[1]]);
                gl_lds16(&A[aoff[0] + ko2], &lds[buf][0][lsl[0]]);
            }
            __builtin_amdgcn_s_barrier();
            __builtin_amdgcn_s_setprio(1);
#pragma unroll
            for (int mt = 0; mt < 4; ++mt)
#pragma unroll
                for (int nt = 0; nt < 4; ++nt)
                    acc[4 + mt][nt] = __builtin_amdgcn_mfma_f32_16x16x32_bf16(af[mt], bfr[nt][1], acc[4 + mt][nt], 0, 0, 0);
            __builtin_amdgcn_s_setprio(0);
            __builtin_amdgcn_sched_barrier(0);
            __builtin_amdgcn_s_barrier();
        }
        // ---- P4: (mh=1, kk=0), B frags reused; stage B slots 2,3 + A slot 2 of t+2 ----
        {
            int cb = lg;
            s16x8 af[4];
#pragma unroll
            for (int mt = 0; mt < 4; ++mt) {
                int r = wm * 128 + 64 + mt * 16 + la;
                af[mt] = *(const s16x8*)&Ab[r * 64 + ((cb ^ (r & 7)) * 8)];
            }
            if (t < 6) {
                gl_lds16(&B[boff[2] + ko2], &lds[buf][1][lsl[2]]);
                gl_lds16(&B[boff[3] + ko2], &lds[buf][1][lsl[3]]);
                gl_lds16(&A[aoff[2] + ko2], &lds[buf][0][lsl[2]]);
            }
            __builtin_amdgcn_s_barrier();
            __builtin_amdgcn_s_setprio(1);
#pragma unroll
            for (int mt = 0; mt < 4; ++mt)
#pragma unroll
                for (int nt = 0; nt < 4; ++nt)
                    acc[4 + mt][nt] = __builtin_amdgcn_mfma_f32_16x16x32_bf16(af[mt], bfr[nt][0], acc[4 + mt][nt], 0, 0, 0);
            __builtin_amdgcn_s_setprio(0);
            __builtin_amdgcn_sched_barrier(0);
            __builtin_amdgcn_s_barrier();
            // A slots 1,3 (mh=1 rows) now fully consumed
        }
        // ---- tile end: finish stage of t+2, counted wait, publish t+1 ----
        if (t < 6) {
            gl_lds16(&A[aoff[1] + ko2], &lds[buf][0][lsl[1]]);
            gl_lds16(&A[aoff[3] + ko2], &lds[buf][0][lsl[3]]);
            asm volatile("s_waitcnt vmcnt(8)" ::: "memory");   // t+1 landed; t+2 in flight
            __builtin_amdgcn_s_barrier();
            asm volatile("" ::: "memory");
        } else if (t == 6) {
            asm volatile("s_waitcnt vmcnt(0)" ::: "memory");   // drain: tile 7 landed
            __builtin_amdgcn_s_barrier();
            asm volatile("" ::: "memory");
        }
    }

#pragma unroll
    for (int mt = 0; mt < 8; ++mt) {
#pragma unroll
        for (int nt = 0; nt < 4; ++nt) {
            int col = n0 + wn * 64 + nt * 16 + la;
#pragma unroll
            for (int rr = 0; rr < 4; ++rr) {
                int r = m0 + wm * 128 + mt * 16 + lg * 4 + rr;
                C[(long)r * 1024 + col] = f2bf(acc[mt][nt][rr]);
            }
        }
    }
}

// ---------------- windowed attention: 1 wave per (window, head), KV interleaved ----------------
__global__ __launch_bounds__(64) void attn_kernel(
    const u16* __restrict__ Q, const u16* __restrict__ KV, u16* __restrict__ O) {
    __shared__ u16 P[16 * 104];
    int bid = blockIdx.x;
    int wg = (bid & 7) * 1024 + (bid >> 3);  // same-window heads colocate on an XCD
    int win = wg >> 3;
    int h = wg & 7;
    int lane = threadIdx.x;
    int la = lane & 15, lg = lane >> 4;
    const u16* Qb = Q + (long)win * 16 * 512 + h * 64;
    const u16* Kb = KV + (long)win * 64 * 1024 + h * 64;
    const u16* Vb = KV + (long)win * 64 * 1024 + 512 + h * 64;

    s16x8 qf[2];
#pragma unroll
    for (int kk = 0; kk < 2; ++kk)
        qf[kk] = *(const s16x8*)&Qb[la * 512 + kk * 32 + lg * 8];

    const f32x4 z = {0.f, 0.f, 0.f, 0.f};
    f32x4 st[4];
#pragma unroll
    for (int rt = 0; rt < 4; ++rt) st[rt] = z;
#pragma unroll
    for (int rt = 0; rt < 4; ++rt)
#pragma unroll
        for (int kk = 0; kk < 2; ++kk) {
            s16x8 kf = *(const s16x8*)&Kb[(rt * 16 + la) * 1024 + kk * 32 + lg * 8];
            st[rt] = __builtin_amdgcn_mfma_f32_16x16x32_bf16(kf, qf[kk], st[rt], 0, 0, 0);
        }
    float mloc = -1e30f;
#pragma unroll
    for (int rt = 0; rt < 4; ++rt)
#pragma unroll
        for (int rr = 0; rr < 4; ++rr) {
            st[rt][rr] *= 0.125f;
            mloc = fmaxf(mloc, st[rt][rr]);
        }
    mloc = fmaxf(mloc, __shfl_xor(mloc, 16));
    mloc = fmaxf(mloc, __shfl_xor(mloc, 32));
    float p[4][4];
    float sloc = 0.f;
#pragma unroll
    for (int rt = 0; rt < 4; ++rt)
#pragma unroll
        for (int rr = 0; rr < 4; ++rr) {
            p[rt][rr] = __expf(st[rt][rr] - mloc);
            sloc += p[rt][rr];
        }
    sloc += __shfl_xor(sloc, 16);
    sloc += __shfl_xor(sloc, 32);
    float inv = 1.0f / sloc;
#pragma unroll
    for (int rt = 0; rt < 4; ++rt)
#pragma unroll
        for (int rr = 0; rr < 4; ++rr)
            P[la * 104 + rt * 16 + lg * 4 + rr] = f2bf(p[rt][rr] * inv);
    __syncthreads();

    f32x4 od[4];
#pragma unroll
    for (int dt = 0; dt < 4; ++dt) od[dt] = z;
#pragma unroll
    for (int kk2 = 0; kk2 < 2; ++kk2) {
        s16x8 pa = *(const s16x8*)&P[la * 104 + kk2 * 32 + lg * 8];
#pragma unroll
        for (int dt = 0; dt < 4; ++dt) {
            s16x8 vb;
#pragma unroll
            for (int j = 0; j < 8; ++j)
                vb[j] = (short)Vb[(long)(kk2 * 32 + lg * 8 + j) * 1024 + dt * 16 + la];
            od[dt] = __builtin_amdgcn_mfma_f32_16x16x32_bf16(pa, vb, od[dt], 0, 0, 0);
        }
    }
    u16* Ob = O + (long)win * 16 * 512 + h * 64;
#pragma unroll
    for (int dt = 0; dt < 4; ++dt)
#pragma unroll
        for (int rr = 0; rr < 4; ++rr)
            Ob[(long)(lg * 4 + rr) * 512 + dt * 16 + la] = f2bf(od[dt][rr]);
}

__global__ void sentinel_kernel(float* out) {
    if (threadIdx.x == 0 && blockIdx.x == 0) out[0] = -12345.0f;
}

extern "C" void kernel_launch(void* const* d_in, const int* in_sizes, int n_in,
                              void* d_out, int out_size, void* d_ws, size_t ws_size,
                              hipStream_t stream) {
    const float* x   = (const float*)d_in[0];
    const float* ctx = (const float*)d_in[1];
    const float* Wq  = (const float*)d_in[2];
    const float* Wk  = (const float*)d_in[3];
    const float* Wv  = (const float*)d_in[4];
    const float* Wo  = (const float*)d_in[5];
    const float* bo  = (const float*)d_in[6];
    float* out = (float*)d_out;

    u16* wsb  = (u16*)d_ws;
    u16* WT   = wsb;                    // 4 * 512*512
    u16* Aq   = WT + 4l * 262144;       // 16384*512
    u16* Actx = Aq + 8388608l;          // 65536*512
    u16* Qb   = Actx + 33554432l;       // 16384*512
    u16* KVb  = Qb + 8388608l;          // 65536*1024 (K cols 0..511, V cols 512..1023)
    u16* Ob   = KVb + 67108864l;        // 16384*512
    size_t need = (size_t)(126877696l) * 2;
    if (ws_size < need) {
        sentinel_kernel<<<1, 64, 0, stream>>>(out);
        return;
    }

    wtrans_kernel<<<256, 256, 0, stream>>>(Wq, Wk, Wv, Wo, WT);
    permx_kernel<<<4096, 256, 0, stream>>>(x, Aq);
    permc_kernel<<<8192, 256, 0, stream>>>(ctx, Actx);
    gemm128_kernel<0><<<512, 256, 0, stream>>>(Aq, WT, Qb, nullptr, nullptr);
    gemmkv256_kernel<<<1024, 512, 0, stream>>>(Actx, WT + 262144l, KVb);
    attn_kernel<<<8192, 64, 0, stream>>>(Qb, KVb, Ob);
    gemm128_kernel<1><<<512, 256, 0, stream>>>(Ob, WT + 3l * 262144, nullptr, out, bo);
}